// Round 7
// baseline (562.596 us; speedup 1.0000x reference)
//
#include <hip/hip_runtime.h>
#include <cfloat>
#include <cmath>
#include <cstdint>

#define NN 10000
#define EE 160000
#define ETOT 170000   // EE + NN self loops
#define MPAD 10112    // 79*128

typedef _Float16 f16;
typedef __attribute__((ext_vector_type(8))) _Float16 f16x8;
typedef __attribute__((ext_vector_type(4))) _Float16 f16x4;
typedef __attribute__((ext_vector_type(2))) _Float16 f16x2;
typedef __attribute__((ext_vector_type(4))) float f32x4;

// ---------------------------------------------------------------- CSR build
__global__ __launch_bounds__(256) void count_deg_k(const int* __restrict__ ei,
                                                   int* __restrict__ deg) {
    int e = blockIdx.x * 256 + threadIdx.x;
    if (e < ETOT) {
        int dst = (e < EE) ? ei[EE + e] : (e - EE);
        atomicAdd(&deg[dst], 1);
    }
}

__global__ __launch_bounds__(256) void sc1_k(const int* __restrict__ deg,
                                             int* __restrict__ tmp,
                                             int* __restrict__ bsum) {
    __shared__ int s[256];
    int i = blockIdx.x * 256 + threadIdx.x;
    int v = (i < NN) ? deg[i] : 0;
    s[threadIdx.x] = v;
    __syncthreads();
    for (int d = 1; d < 256; d <<= 1) {
        int t = (threadIdx.x >= d) ? s[threadIdx.x - d] : 0;
        __syncthreads();
        s[threadIdx.x] += t;
        __syncthreads();
    }
    if (i < NN) tmp[i] = s[threadIdx.x];
    if (threadIdx.x == 255) bsum[blockIdx.x] = s[255];
}

__global__ __launch_bounds__(64) void sc2_k(const int* __restrict__ bsum,
                                            int* __restrict__ bbase) {
    int lane = threadIdx.x;
    int v = (lane < 40) ? bsum[lane] : 0;
    int incl = v;
    for (int d = 1; d < 64; d <<= 1) {
        int t = __shfl_up(incl, d, 64);
        if (lane >= d) incl += t;
    }
    if (lane < 40) bbase[lane] = incl - v;
}

__global__ __launch_bounds__(256) void sc3_k(const int* __restrict__ deg,
                                             const int* __restrict__ tmp,
                                             const int* __restrict__ bbase,
                                             int* __restrict__ offs,
                                             int* __restrict__ pos) {
    int i = blockIdx.x * 256 + threadIdx.x;
    if (i < NN) {
        int incl = tmp[i] + bbase[blockIdx.x];
        offs[i + 1] = incl;
        pos[i]      = incl - deg[i];
    }
    if (i == 0) offs[0] = 0;
}

__global__ __launch_bounds__(256) void scatter_k(const int* __restrict__ ei,
                                                 int* __restrict__ pos,
                                                 int* __restrict__ esrc) {
    int e = blockIdx.x * 256 + threadIdx.x;
    if (e < ETOT) {
        int dst = (e < EE) ? ei[EE + e] : (e - EE);
        int src = (e < EE) ? ei[e]      : (e - EE);
        int p = atomicAdd(&pos[dst], 1);
        esrc[p] = src;
    }
}

// --------------------------------------------- fp32 -> tiled f16 hi/lo
// Tile = 128 rows x 32 k (8KB). Row r at r*64B; 16B chunk ko at ko^((r>>1)&3).
__device__ __forceinline__ int swz(int r, int ko) { return ko ^ ((r >> 1) & 3); }

template <bool DOELU>
__global__ __launch_bounds__(256) void convA_k(const float* __restrict__ A,
                                               f16* __restrict__ hi,
                                               f16* __restrict__ lo,
                                               int M, int K, int kshift) {
    int idx = blockIdx.x * 256 + threadIdx.x;
    int row = idx >> kshift;
    int kc  = idx & ((1 << kshift) - 1);
    float v[8];
    if (row < M) {
        const float* p = A + (size_t)row * K + kc * 8;
        float4 f0 = *(const float4*)p, f1 = *(const float4*)(p + 4);
        v[0]=f0.x; v[1]=f0.y; v[2]=f0.z; v[3]=f0.w;
        v[4]=f1.x; v[5]=f1.y; v[6]=f1.z; v[7]=f1.w;
        if (DOELU) {
#pragma unroll
            for (int i = 0; i < 8; i++) v[i] = (v[i] > 0.f) ? v[i] : expf(v[i]) - 1.f;
        }
    } else {
#pragma unroll
        for (int i = 0; i < 8; i++) v[i] = 0.f;
    }
    int mblk = row >> 7, r = row & 127;
    int kblk = kc >> 2,  ko = kc & 3;
    int KB = K >> 5;
    size_t off = ((size_t)(mblk * KB + kblk)) * 4096 + r * 32 + swz(r, ko) * 8;
    f16x8 h, l;
#pragma unroll
    for (int i = 0; i < 8; i++) {
        f16 hv = (f16)v[i];
        h[i] = hv;
        l[i] = (f16)(v[i] - (float)hv);
    }
    *(f16x8*)(hi + off) = h;
    *(f16x8*)(lo + off) = l;
}

// B [K,NcSrc] fp32 -> transposed tiled f16 (hi only)
__global__ __launch_bounds__(256) void convB_k(const float* __restrict__ B,
                                               f16* __restrict__ Bdst,
                                               int NcSrc, int colOff, int KB) {
    int n  = blockIdx.x * 256 + threadIdx.x;
    int kc = blockIdx.y;
    const float* p = B + (size_t)(kc * 8) * NcSrc + n;
    int gcol = colOff + n;
    int nblk = gcol >> 7, r = gcol & 127;
    int kblk = kc >> 2,  ko = kc & 3;
    size_t off = ((size_t)(nblk * KB + kblk)) * 4096 + r * 32 + swz(r, ko) * 8;
    f16x8 h;
#pragma unroll
    for (int i = 0; i < 8; i++) h[i] = (f16)p[(size_t)i * NcSrc];
    *(f16x8*)(Bdst + off) = h;
}

// ---------------------------------------------------------- f16 MFMA GEMM
// C = (Ahi+Alo)*Bhi. 128x128 tile, BK=32, 4 waves (2x2), wave = 64x64.
// 2-phase pipeline: double-buffered LDS, stage(next) issued BEFORE compute,
// single __syncthreads per K-step (vmcnt drain lands after compute).
__device__ __forceinline__ void gl_lds16(const void* g, void* l) {
    __builtin_amdgcn_global_load_lds(
        (const __attribute__((address_space(1))) uint32_t*)g,
        (__attribute__((address_space(3))) uint32_t*)l, 16, 0, 0);
}

#define MMBUF 24576

__global__ __launch_bounds__(256) void mm_k(const f16* __restrict__ Ahi,
                                            const f16* __restrict__ Alo,
                                            const f16* __restrict__ Bhi,
                                            float* __restrict__ C2,
                                            f16* __restrict__ C1h,
                                            const float* __restrict__ bias1,
                                            const float* __restrict__ bias2,
                                            const float* __restrict__ a_s,
                                            const float* __restrict__ a_d,
                                            float* __restrict__ als,
                                            float* __restrict__ ald,
                                            int M, int KB, int NB1,
                                            int N1, int N2, int H) {
    __shared__ __align__(16) char lds[2 * MMBUF];  // per buf: Ahi|Alo|Bhi 8KB each
    const int tid = threadIdx.x;

    // bijective XCD chunking: consecutive remapped ids share mblk on one XCD
    const int nwg  = gridDim.x * gridDim.y;
    const int orig = blockIdx.y * gridDim.x + blockIdx.x;
    const int q = nwg >> 3, rr = nwg & 7;
    const int xcd = orig & 7, rk = orig >> 3;
    const int lin = (xcd < rr ? xcd * (q + 1) : rr * (q + 1) + (xcd - rr) * q) + rk;
    const int mblk = lin / gridDim.x, nblk = lin % gridDim.x;

    const int lane = tid & 63, w = tid >> 6;
    const int wr = w >> 1, wc = w & 1;
    const int kg = lane >> 4, l15 = lane & 15;

    int offA[4], offB[4];
#pragma unroll
    for (int t = 0; t < 4; t++) {
        int ra = wr * 64 + t * 16 + l15;
        offA[t] = ra * 64 + swz(ra, kg) * 16;
        int rb = wc * 64 + t * 16 + l15;
        offB[t] = 16384 + rb * 64 + swz(rb, kg) * 16;
    }

    const char* gAh = (const char*)Ahi + (size_t)mblk * KB * 8192;
    const char* gAl = (const char*)Alo + (size_t)mblk * KB * 8192;
    const char* gBh = (const char*)Bhi + (size_t)nblk * KB * 8192;

    f32x4 acc[4][4];
#pragma unroll
    for (int i = 0; i < 4; i++)
#pragma unroll
        for (int j = 0; j < 4; j++) acc[i][j] = (f32x4){0.f, 0.f, 0.f, 0.f};

    const int t16 = tid * 16;
    auto stage = [&](int kb, int buf) {
        const size_t tk = (size_t)kb * 8192;
        char* l = lds + buf * MMBUF;
        gl_lds16(gAh + tk + t16,        l + t16);
        gl_lds16(gAh + tk + 4096 + t16, l + 4096 + t16);
        gl_lds16(gAl + tk + t16,        l + 8192 + t16);
        gl_lds16(gAl + tk + 4096 + t16, l + 12288 + t16);
        gl_lds16(gBh + tk + t16,        l + 16384 + t16);
        gl_lds16(gBh + tk + 4096 + t16, l + 20480 + t16);
    };

    stage(0, 0);
    __syncthreads();   // vmcnt(0)+lgkmcnt(0)+barrier

    for (int kb = 0; kb < KB; kb++) {
        const int cur = kb & 1;
        if (kb + 1 < KB) stage(kb + 1, cur ^ 1);   // in flight across compute

        const char* l = lds + cur * MMBUF;
        f16x8 ah[4], al[4], b[4];
#pragma unroll
        for (int t = 0; t < 4; t++) {
            ah[t] = *(const f16x8*)(l + offA[t]);
            al[t] = *(const f16x8*)(l + 8192 + offA[t]);
            b[t]  = *(const f16x8*)(l + offB[t]);
        }
#pragma unroll
        for (int i = 0; i < 4; i++)
#pragma unroll
            for (int j = 0; j < 4; j++) {
                acc[i][j] = __builtin_amdgcn_mfma_f32_16x16x32_f16(ah[i], b[j], acc[i][j], 0, 0, 0);
                acc[i][j] = __builtin_amdgcn_mfma_f32_16x16x32_f16(al[i], b[j], acc[i][j], 0, 0, 0);
            }
        __syncthreads();   // drains next-tile loads (latency covered by MFMA)
    }

    const int rowBase = mblk * 128 + wr * 64;
    const int colBase = nblk * 128 + wc * 64;
    if (nblk < NB1) {
        // f16 feature write (garbage pad rows never read downstream)
#pragma unroll
        for (int i = 0; i < 4; i++)
#pragma unroll
            for (int j = 0; j < 4; j++) {
                int col = colBase + j * 16 + l15;
#pragma unroll
                for (int q2 = 0; q2 < 4; q2++) {
                    int row = rowBase + i * 16 + kg * 4 + q2;
                    C1h[(size_t)row * N1 + col] = (f16)acc[i][j][q2];
                }
            }
        // fused attention logits: nblk covers half of one 256-col head
        const int head = nblk >> 1;
        const int cIn  = (nblk & 1) * 128 + wc * 64;
        float asv[4], adv[4];
#pragma unroll
        for (int j = 0; j < 4; j++) {
            asv[j] = a_s[head * 256 + cIn + j * 16 + l15];
            adv[j] = a_d[head * 256 + cIn + j * 16 + l15];
        }
#pragma unroll
        for (int i = 0; i < 4; i++)
#pragma unroll
            for (int q2 = 0; q2 < 4; q2++) {
                float vs = acc[i][0][q2] * asv[0] + acc[i][1][q2] * asv[1]
                         + acc[i][2][q2] * asv[2] + acc[i][3][q2] * asv[3];
                float vd = acc[i][0][q2] * adv[0] + acc[i][1][q2] * adv[1]
                         + acc[i][2][q2] * adv[2] + acc[i][3][q2] * adv[3];
                vs += __shfl_xor(vs, 1); vs += __shfl_xor(vs, 2);
                vs += __shfl_xor(vs, 4); vs += __shfl_xor(vs, 8);
                vd += __shfl_xor(vd, 1); vd += __shfl_xor(vd, 2);
                vd += __shfl_xor(vd, 4); vd += __shfl_xor(vd, 8);
                if (l15 == 0) {
                    int row = rowBase + i * 16 + kg * 4 + q2;
                    if (row < M) {
                        atomicAdd(&als[row * H + head], vs);
                        atomicAdd(&ald[row * H + head], vd);
                    }
                }
            }
    } else {
        const int cb2 = NB1 * 128;
#pragma unroll
        for (int i = 0; i < 4; i++)
#pragma unroll
            for (int j = 0; j < 4; j++) {
                int c2 = colBase + j * 16 + l15 - cb2;
                float bsum = bias1[c2] + bias2[c2];
#pragma unroll
                for (int q2 = 0; q2 < 4; q2++) {
                    int row = rowBase + i * 16 + kg * 4 + q2;
                    if (row < M) C2[(size_t)row * N2 + c2] = acc[i][j][q2] + bsum;
                }
            }
    }
}

// --------------------------- fused edge-softmax + aggregation (per node)
// Column-contiguous ownership for vectorized gathers:
//  H=4: thread owns cols 4t..4t+3 (one head), f16x4 loads.
//  H=6: thread owns col pairs {2t,2t+512,2t+1024}(+1), 3x f16x2 loads,
//       head-mean via (t, t+128) LDS pair-reduction.
// Concat epilogue: skip + agg -> ELU -> next layer's tiled hi/lo A.
template <int H, bool MEAN>
__global__ __launch_bounds__(256) void smagg_k(const int* __restrict__ offs,
                                               const int* __restrict__ esrc,
                                               const float* __restrict__ als,
                                               const float* __restrict__ ald,
                                               const f16* __restrict__ hfeat16,
                                               const float* __restrict__ skipin,
                                               float* __restrict__ outf,
                                               f16* __restrict__ hiT,
                                               f16* __restrict__ loT) {
    constexpr int NC = H * 256;
    __shared__ float s_l[128 * 9];
    __shared__ float s_p[128 * 9];
    __shared__ int   s_src[128];
    __shared__ float s_m[8], s_s[8], s_scale[8], s_ad[8];
    __shared__ float s_red[256];

    const int n = blockIdx.x;
    const int tid = threadIdx.x;
    const int base = offs[n], cnt = offs[n + 1] - base;

    if (tid < H) {
        s_m[tid] = -1e30f;
        s_s[tid] = 0.f;
        s_ad[tid] = ald[n * H + tid];
    }

    // per-thread column ownership
    float acc4[4] = {0.f, 0.f, 0.f, 0.f};          // H=4 path
    float acc6[3][2] = {{0.f,0.f},{0.f,0.f},{0.f,0.f}};  // H=6 path
    const int c0 = tid * 4;          // H=4
    const int h0 = c0 >> 8;
    const int cb = tid * 2;          // H=6
    int hB[3];
#pragma unroll
    for (int b = 0; b < 3; b++) hB[b] = (cb + 512 * b) >> 8;
    __syncthreads();

    for (int ch0 = 0; ch0 < cnt; ch0 += 128) {
        const int mcnt = min(128, cnt - ch0);
        // (a) logits (vector gather of als)
        if (tid < mcnt) {
            int src = esrc[base + ch0 + tid];
            s_src[tid] = src;
            if (H == 4) {
                float4 a4 = *(const float4*)(als + (size_t)src * 4);
                float l0 = a4.x + s_ad[0], l1 = a4.y + s_ad[1];
                float l2 = a4.z + s_ad[2], l3 = a4.w + s_ad[3];
                s_l[tid * 9 + 0] = (l0 < 0.f) ? 0.2f * l0 : l0;
                s_l[tid * 9 + 1] = (l1 < 0.f) ? 0.2f * l1 : l1;
                s_l[tid * 9 + 2] = (l2 < 0.f) ? 0.2f * l2 : l2;
                s_l[tid * 9 + 3] = (l3 < 0.f) ? 0.2f * l3 : l3;
            } else {
                const float2* ap = (const float2*)(als + (size_t)src * 6);
#pragma unroll
                for (int b = 0; b < 3; b++) {
                    float2 a2 = ap[b];
                    float l0 = a2.x + s_ad[2 * b], l1 = a2.y + s_ad[2 * b + 1];
                    s_l[tid * 9 + 2 * b]     = (l0 < 0.f) ? 0.2f * l0 : l0;
                    s_l[tid * 9 + 2 * b + 1] = (l1 < 0.f) ? 0.2f * l1 : l1;
                }
            }
        }
        __syncthreads();
        // (b) per-head running max + sum
        if (tid < H * 32) {
            int h = tid >> 5, l5 = tid & 31;
            float m = -1e30f;
            for (int e = l5; e < mcnt; e += 32) m = fmaxf(m, s_l[e * 9 + h]);
            for (int o = 16; o > 0; o >>= 1) m = fmaxf(m, __shfl_xor(m, o, 32));
            float mNew = fmaxf(s_m[h], m);
            float ssum = 0.f;
            for (int e = l5; e < mcnt; e += 32) ssum += __expf(s_l[e * 9 + h] - mNew);
            for (int o = 16; o > 0; o >>= 1) ssum += __shfl_xor(ssum, o, 32);
            if (l5 == 0) {
                float scale = __expf(s_m[h] - mNew);
                s_scale[h] = scale;
                s_s[h] = s_s[h] * scale + ssum;
                s_m[h] = mNew;
            }
        }
        __syncthreads();
        // (c) unnormalized probabilities
        if (tid < mcnt) {
#pragma unroll
            for (int h = 0; h < H; h++)
                s_p[tid * 9 + h] = __expf(s_l[tid * 9 + h] - s_m[h]);
        }
        if (H == 4) {
            float sc = s_scale[h0];
#pragma unroll
            for (int i = 0; i < 4; i++) acc4[i] *= sc;
        } else {
#pragma unroll
            for (int b = 0; b < 3; b++) {
                float sc = s_scale[hB[b]];
                acc6[b][0] *= sc; acc6[b][1] *= sc;
            }
        }
        __syncthreads();
        // (d) vectorized aggregation
        if (H == 4) {
            for (int e = 0; e < mcnt; e++) {
                f16x4 v = *(const f16x4*)(hfeat16 + (size_t)s_src[e] * 1024 + c0);
                float p = s_p[e * 9 + h0];
                acc4[0] += p * (float)v[0];
                acc4[1] += p * (float)v[1];
                acc4[2] += p * (float)v[2];
                acc4[3] += p * (float)v[3];
            }
        } else {
            for (int e = 0; e < mcnt; e++) {
                const f16* hp = hfeat16 + (size_t)s_src[e] * 1536 + cb;
#pragma unroll
                for (int b = 0; b < 3; b++) {
                    f16x2 v = *(const f16x2*)(hp + 512 * b);
                    float p = s_p[e * 9 + hB[b]];
                    acc6[b][0] += p * (float)v[0];
                    acc6[b][1] += p * (float)v[1];
                }
            }
        }
        __syncthreads();
    }

    if (MEAN) {
        // normalize, sum heads across col-pair partners (t, t+128)
        float p0 = 0.f, p1 = 0.f;
#pragma unroll
        for (int b = 0; b < 3; b++) {
            float inv = 1.f / (s_s[hB[b]] + 1e-16f);
            p0 += acc6[b][0] * inv;
            p1 += acc6[b][1] * inv;
        }
        if (tid >= 128) {
            s_red[2 * (tid - 128)]     = p0;
            s_red[2 * (tid - 128) + 1] = p1;
        }
        __syncthreads();
        if (tid < 128) {
            p0 += s_red[2 * tid];
            p1 += s_red[2 * tid + 1];
            float2* op = (float2*)(outf + (size_t)n * 256 + 2 * tid);
            float2 prev = *op;
            prev.x += p0 * (1.f / 6.f);
            prev.y += p1 * (1.f / 6.f);
            *op = prev;
        }
    } else {
        // skip + agg -> ELU -> tiled hi/lo write (f16x4)
        const int mblk = n >> 7, r = n & 127;
        float4 sk = *(const float4*)(skipin + (size_t)n * NC + c0);
        float inv = 1.f / (s_s[h0] + 1e-16f);
        float v[4] = {sk.x + acc4[0] * inv, sk.y + acc4[1] * inv,
                      sk.z + acc4[2] * inv, sk.w + acc4[3] * inv};
        f16x4 hv, lv;
#pragma unroll
        for (int i = 0; i < 4; i++) {
            float e = (v[i] > 0.f) ? v[i] : expf(v[i]) - 1.f;
            f16 h = (f16)e;
            hv[i] = h;
            lv[i] = (f16)(e - (float)h);
        }
        int kblk = c0 >> 5, ko = (c0 >> 3) & 3, elem = c0 & 7;
        size_t off = ((size_t)(mblk * 32 + kblk)) * 4096
                   + r * 32 + swz(r, ko) * 8 + elem;
        *(f16x4*)(hiT + off) = hv;
        *(f16x4*)(loT + off) = lv;
    }
}

// ------------------------------------------------------------------ driver
extern "C" void kernel_launch(void* const* d_in, const int* in_sizes, int n_in,
                              void* d_out, int out_size, void* d_ws, size_t ws_size,
                              hipStream_t stream) {
    const float* x   = (const float*)d_in[0];
    const int*   ei  = (const int*)d_in[1];
    const float* W1  = (const float*)d_in[2];
    const float* a1s = (const float*)d_in[3];
    const float* a1d = (const float*)d_in[4];
    const float* b1  = (const float*)d_in[5];
    const float* S1w = (const float*)d_in[6];
    const float* S1b = (const float*)d_in[7];
    const float* W2  = (const float*)d_in[8];
    const float* a2s = (const float*)d_in[9];
    const float* a2d = (const float*)d_in[10];
    const float* b2  = (const float*)d_in[11];
    const float* S2w = (const float*)d_in[12];
    const float* S2b = (const float*)d_in[13];
    const float* W3  = (const float*)d_in[14];
    const float* a3s = (const float*)d_in[15];
    const float* a3d = (const float*)d_in[16];
    const float* b3  = (const float*)d_in[17];
    const float* S3w = (const float*)d_in[18];
    const float* S3b = (const float*)d_in[19];
    float* out = (float*)d_out;

    float* ws = (float*)d_ws;
    size_t o = 0;
    float* bufA = ws + o; o += (size_t)NN * 1024;   // skip outputs (C2)
    float* bufB = ws + o; o += (size_t)NN * 1024;
    float* als  = ws + o; o += (size_t)NN * 6;
    float* ald  = ws + o; o += (size_t)NN * 6;
    f16* hfeat16 = (f16*)(ws + o); o += (size_t)MPAD * 1536 / 2;
    f16* AhiT = (f16*)(ws + o); o += (size_t)MPAD * 1024 / 2;
    f16* AloT = (f16*)(ws + o); o += (size_t)MPAD * 1024 / 2;
    f16* Bt1  = (f16*)(ws + o); o += (size_t)16 * 4  * 4096 / 2;
    f16* Bt2  = (f16*)(ws + o); o += (size_t)16 * 32 * 4096 / 2;
    f16* Bt3  = (f16*)(ws + o); o += (size_t)14 * 32 * 4096 / 2;
    int* deg   = (int*)(ws + o);
    int* tmp   = deg + NN;
    int* bsum  = tmp + NN;
    int* bbase = bsum + 64;
    int* offs  = bbase + 64;
    int* pos   = offs + NN + 1;
    int* esrc  = pos + NN;

    // ---- CSR by dst (shared by all 3 layers)
    hipMemsetAsync(deg, 0, NN * sizeof(int), stream);
    count_deg_k<<<(ETOT + 255) / 256, 256, 0, stream>>>(ei, deg);
    sc1_k<<<40, 256, 0, stream>>>(deg, tmp, bsum);
    sc2_k<<<1, 64, 0, stream>>>(bsum, bbase);
    sc3_k<<<40, 256, 0, stream>>>(deg, tmp, bbase, offs, pos);
    scatter_k<<<(ETOT + 255) / 256, 256, 0, stream>>>(ei, pos, esrc);

    // ---- weight conversion (merged per-layer B = [W | S], hi only)
    convB_k<<<dim3(4, 16),  256, 0, stream>>>(W1,  Bt1, 1024, 0,    4);
    convB_k<<<dim3(4, 16),  256, 0, stream>>>(S1w, Bt1, 1024, 1024, 4);
    convB_k<<<dim3(4, 128), 256, 0, stream>>>(W2,  Bt2, 1024, 0,    32);
    convB_k<<<dim3(4, 128), 256, 0, stream>>>(S2w, Bt2, 1024, 1024, 32);
    convB_k<<<dim3(6, 128), 256, 0, stream>>>(W3,  Bt3, 1536, 0,    32);
    convB_k<<<dim3(1, 128), 256, 0, stream>>>(S3w, Bt3, 256,  1536, 32);

    // ---- Layer 1: A=x [N,128], N=2048 (8 blk feat | 8 blk skip)
    convA_k<false><<<MPAD * 16 / 256, 256, 0, stream>>>(x, AhiT, AloT, NN, 128, 4);
    hipMemsetAsync(als, 0, NN * 12 * sizeof(float), stream);
    mm_k<<<dim3(16, 79), 256, 0, stream>>>(AhiT, AloT, Bt1, bufA, hfeat16, S1b, b1,
                                           a1s, a1d, als, ald,
                                           NN, 4, 8, 1024, 1024, 4);
    // smagg writes layer-2's tiled A (ELU fused), consuming skip from bufA
    smagg_k<4, false><<<NN, 256, 0, stream>>>(offs, esrc, als, ald, hfeat16,
                                              bufA, nullptr, AhiT, AloT);

    // ---- Layer 2
    hipMemsetAsync(als, 0, NN * 12 * sizeof(float), stream);
    mm_k<<<dim3(16, 79), 256, 0, stream>>>(AhiT, AloT, Bt2, bufB, hfeat16, S2b, b2,
                                           a2s, a2d, als, ald,
                                           NN, 32, 8, 1024, 1024, 4);
    smagg_k<4, false><<<NN, 256, 0, stream>>>(offs, esrc, als, ald, hfeat16,
                                              bufB, nullptr, AhiT, AloT);

    // ---- Layer 3: N=1792 (12 blk feat | 2 blk skip->out), mean over 6 heads
    hipMemsetAsync(als, 0, NN * 12 * sizeof(float), stream);
    mm_k<<<dim3(14, 79), 256, 0, stream>>>(AhiT, AloT, Bt3, out, hfeat16, S3b, b3,
                                           a3s, a3d, als, ald,
                                           NN, 32, 12, 1536, 256, 6);
    smagg_k<6, true><<<NN, 256, 0, stream>>>(offs, esrc, als, ald, hfeat16,
                                             nullptr, out, nullptr, nullptr);
}

// Round 8
// 561.508 us; speedup vs baseline: 1.0019x; 1.0019x over previous
//
#include <hip/hip_runtime.h>
#include <cfloat>
#include <cmath>
#include <cstdint>

#define NN 10000
#define EE 160000
#define ETOT 170000   // EE + NN self loops
#define MPAD 10112    // 79*128

typedef _Float16 f16;
typedef __attribute__((ext_vector_type(8))) _Float16 f16x8;
typedef __attribute__((ext_vector_type(4))) float f32x4;

// ---------------------------------------------------------------- CSR build
__global__ __launch_bounds__(256) void count_deg_k(const int* __restrict__ ei,
                                                   int* __restrict__ deg) {
    int e = blockIdx.x * 256 + threadIdx.x;
    if (e < ETOT) {
        int dst = (e < EE) ? ei[EE + e] : (e - EE);
        atomicAdd(&deg[dst], 1);
    }
}

__global__ __launch_bounds__(256) void sc1_k(const int* __restrict__ deg,
                                             int* __restrict__ tmp,
                                             int* __restrict__ bsum) {
    __shared__ int s[256];
    int i = blockIdx.x * 256 + threadIdx.x;
    int v = (i < NN) ? deg[i] : 0;
    s[threadIdx.x] = v;
    __syncthreads();
    for (int d = 1; d < 256; d <<= 1) {
        int t = (threadIdx.x >= d) ? s[threadIdx.x - d] : 0;
        __syncthreads();
        s[threadIdx.x] += t;
        __syncthreads();
    }
    if (i < NN) tmp[i] = s[threadIdx.x];
    if (threadIdx.x == 255) bsum[blockIdx.x] = s[255];
}

__global__ __launch_bounds__(64) void sc2_k(const int* __restrict__ bsum,
                                            int* __restrict__ bbase) {
    int lane = threadIdx.x;
    int v = (lane < 40) ? bsum[lane] : 0;
    int incl = v;
    for (int d = 1; d < 64; d <<= 1) {
        int t = __shfl_up(incl, d, 64);
        if (lane >= d) incl += t;
    }
    if (lane < 40) bbase[lane] = incl - v;
}

__global__ __launch_bounds__(256) void sc3_k(const int* __restrict__ deg,
                                             const int* __restrict__ tmp,
                                             const int* __restrict__ bbase,
                                             int* __restrict__ offs,
                                             int* __restrict__ pos) {
    int i = blockIdx.x * 256 + threadIdx.x;
    if (i < NN) {
        int incl = tmp[i] + bbase[blockIdx.x];
        offs[i + 1] = incl;
        pos[i]      = incl - deg[i];
    }
    if (i == 0) offs[0] = 0;
}

__global__ __launch_bounds__(256) void scatter_k(const int* __restrict__ ei,
                                                 int* __restrict__ pos,
                                                 int* __restrict__ esrc) {
    int e = blockIdx.x * 256 + threadIdx.x;
    if (e < ETOT) {
        int dst = (e < EE) ? ei[EE + e] : (e - EE);
        int src = (e < EE) ? ei[e]      : (e - EE);
        int p = atomicAdd(&pos[dst], 1);
        esrc[p] = src;
    }
}

// --------------------------------------------- fp32 -> tiled f16 hi/lo
// Tile = 128 rows x 32 k (8KB). Row r at r*64B; 16B chunk ko at ko^((r>>1)&3).
__device__ __forceinline__ int swz(int r, int ko) { return ko ^ ((r >> 1) & 3); }

template <bool DOELU>
__global__ __launch_bounds__(256) void convA_k(const float* __restrict__ A,
                                               f16* __restrict__ hi,
                                               f16* __restrict__ lo,
                                               int M, int K, int kshift) {
    int idx = blockIdx.x * 256 + threadIdx.x;
    int row = idx >> kshift;
    int kc  = idx & ((1 << kshift) - 1);
    float v[8];
    if (row < M) {
        const float* p = A + (size_t)row * K + kc * 8;
        float4 f0 = *(const float4*)p, f1 = *(const float4*)(p + 4);
        v[0]=f0.x; v[1]=f0.y; v[2]=f0.z; v[3]=f0.w;
        v[4]=f1.x; v[5]=f1.y; v[6]=f1.z; v[7]=f1.w;
        if (DOELU) {
#pragma unroll
            for (int i = 0; i < 8; i++) v[i] = (v[i] > 0.f) ? v[i] : expf(v[i]) - 1.f;
        }
    } else {
#pragma unroll
        for (int i = 0; i < 8; i++) v[i] = 0.f;
    }
    int mblk = row >> 7, r = row & 127;
    int kblk = kc >> 2,  ko = kc & 3;
    int KB = K >> 5;
    size_t off = ((size_t)(mblk * KB + kblk)) * 4096 + r * 32 + swz(r, ko) * 8;
    f16x8 h, l;
#pragma unroll
    for (int i = 0; i < 8; i++) {
        f16 hv = (f16)v[i];
        h[i] = hv;
        l[i] = (f16)(v[i] - (float)hv);
    }
    *(f16x8*)(hi + off) = h;
    *(f16x8*)(lo + off) = l;
}

// B [K,NcSrc] fp32 -> transposed tiled f16 (hi only)
__global__ __launch_bounds__(256) void convB_k(const float* __restrict__ B,
                                               f16* __restrict__ Bdst,
                                               int NcSrc, int colOff, int KB) {
    int n  = blockIdx.x * 256 + threadIdx.x;
    int kc = blockIdx.y;
    const float* p = B + (size_t)(kc * 8) * NcSrc + n;
    int gcol = colOff + n;
    int nblk = gcol >> 7, r = gcol & 127;
    int kblk = kc >> 2,  ko = kc & 3;
    size_t off = ((size_t)(nblk * KB + kblk)) * 4096 + r * 32 + swz(r, ko) * 8;
    f16x8 h;
#pragma unroll
    for (int i = 0; i < 8; i++) h[i] = (f16)p[(size_t)i * NcSrc];
    *(f16x8*)(Bdst + off) = h;
}

// ---------------------------------------------------------- f16 MFMA GEMM
// C = (Ahi+Alo)*Bhi. 128x128 tile, BK=32, 4 waves (2x2), wave = 64x64.
// 2-phase pipeline: double-buffered LDS, stage(next) issued BEFORE compute,
// single __syncthreads per K-step (vmcnt drain lands after compute).
__device__ __forceinline__ void gl_lds16(const void* g, void* l) {
    __builtin_amdgcn_global_load_lds(
        (const __attribute__((address_space(1))) uint32_t*)g,
        (__attribute__((address_space(3))) uint32_t*)l, 16, 0, 0);
}

#define MMBUF 24576

__global__ __launch_bounds__(256) void mm_k(const f16* __restrict__ Ahi,
                                            const f16* __restrict__ Alo,
                                            const f16* __restrict__ Bhi,
                                            float* __restrict__ C2,
                                            f16* __restrict__ C1h,
                                            const float* __restrict__ bias1,
                                            const float* __restrict__ bias2,
                                            const float* __restrict__ a_s,
                                            const float* __restrict__ a_d,
                                            float* __restrict__ als,
                                            float* __restrict__ ald,
                                            int M, int KB, int NB1,
                                            int N1, int N2, int H) {
    __shared__ __align__(16) char lds[2 * MMBUF];  // per buf: Ahi|Alo|Bhi 8KB each
    const int tid = threadIdx.x;

    // bijective XCD chunking: consecutive remapped ids share mblk on one XCD
    const int nwg  = gridDim.x * gridDim.y;
    const int orig = blockIdx.y * gridDim.x + blockIdx.x;
    const int q = nwg >> 3, rr = nwg & 7;
    const int xcd = orig & 7, rk = orig >> 3;
    const int lin = (xcd < rr ? xcd * (q + 1) : rr * (q + 1) + (xcd - rr) * q) + rk;
    const int mblk = lin / gridDim.x, nblk = lin % gridDim.x;

    const int lane = tid & 63, w = tid >> 6;
    const int wr = w >> 1, wc = w & 1;
    const int kg = lane >> 4, l15 = lane & 15;

    int offA[4], offB[4];
#pragma unroll
    for (int t = 0; t < 4; t++) {
        int ra = wr * 64 + t * 16 + l15;
        offA[t] = ra * 64 + swz(ra, kg) * 16;
        int rb = wc * 64 + t * 16 + l15;
        offB[t] = 16384 + rb * 64 + swz(rb, kg) * 16;
    }

    const char* gAh = (const char*)Ahi + (size_t)mblk * KB * 8192;
    const char* gAl = (const char*)Alo + (size_t)mblk * KB * 8192;
    const char* gBh = (const char*)Bhi + (size_t)nblk * KB * 8192;

    f32x4 acc[4][4];
#pragma unroll
    for (int i = 0; i < 4; i++)
#pragma unroll
        for (int j = 0; j < 4; j++) acc[i][j] = (f32x4){0.f, 0.f, 0.f, 0.f};

    const int t16 = tid * 16;
    auto stage = [&](int kb, int buf) {
        const size_t tk = (size_t)kb * 8192;
        char* l = lds + buf * MMBUF;
        gl_lds16(gAh + tk + t16,        l + t16);
        gl_lds16(gAh + tk + 4096 + t16, l + 4096 + t16);
        gl_lds16(gAl + tk + t16,        l + 8192 + t16);
        gl_lds16(gAl + tk + 4096 + t16, l + 12288 + t16);
        gl_lds16(gBh + tk + t16,        l + 16384 + t16);
        gl_lds16(gBh + tk + 4096 + t16, l + 20480 + t16);
    };

    stage(0, 0);
    __syncthreads();   // vmcnt(0)+lgkmcnt(0)+barrier

    for (int kb = 0; kb < KB; kb++) {
        const int cur = kb & 1;
        if (kb + 1 < KB) stage(kb + 1, cur ^ 1);   // in flight across compute

        const char* l = lds + cur * MMBUF;
        f16x8 ah[4], al[4], b[4];
#pragma unroll
        for (int t = 0; t < 4; t++) {
            ah[t] = *(const f16x8*)(l + offA[t]);
            al[t] = *(const f16x8*)(l + 8192 + offA[t]);
            b[t]  = *(const f16x8*)(l + offB[t]);
        }
#pragma unroll
        for (int i = 0; i < 4; i++)
#pragma unroll
            for (int j = 0; j < 4; j++) {
                acc[i][j] = __builtin_amdgcn_mfma_f32_16x16x32_f16(ah[i], b[j], acc[i][j], 0, 0, 0);
                acc[i][j] = __builtin_amdgcn_mfma_f32_16x16x32_f16(al[i], b[j], acc[i][j], 0, 0, 0);
            }
        __syncthreads();   // drains next-tile loads (latency covered by MFMA)
    }

    const int rowBase = mblk * 128 + wr * 64;
    const int colBase = nblk * 128 + wc * 64;
    if (nblk < NB1) {
        // f16 feature write (garbage pad rows never read downstream)
#pragma unroll
        for (int i = 0; i < 4; i++)
#pragma unroll
            for (int j = 0; j < 4; j++) {
                int col = colBase + j * 16 + l15;
#pragma unroll
                for (int q2 = 0; q2 < 4; q2++) {
                    int row = rowBase + i * 16 + kg * 4 + q2;
                    C1h[(size_t)row * N1 + col] = (f16)acc[i][j][q2];
                }
            }
        // fused attention logits: nblk covers half of one 256-col head
        const int head = nblk >> 1;
        const int cIn  = (nblk & 1) * 128 + wc * 64;
        float asv[4], adv[4];
#pragma unroll
        for (int j = 0; j < 4; j++) {
            asv[j] = a_s[head * 256 + cIn + j * 16 + l15];
            adv[j] = a_d[head * 256 + cIn + j * 16 + l15];
        }
#pragma unroll
        for (int i = 0; i < 4; i++)
#pragma unroll
            for (int q2 = 0; q2 < 4; q2++) {
                float vs = acc[i][0][q2] * asv[0] + acc[i][1][q2] * asv[1]
                         + acc[i][2][q2] * asv[2] + acc[i][3][q2] * asv[3];
                float vd = acc[i][0][q2] * adv[0] + acc[i][1][q2] * adv[1]
                         + acc[i][2][q2] * adv[2] + acc[i][3][q2] * adv[3];
                vs += __shfl_xor(vs, 1); vs += __shfl_xor(vs, 2);
                vs += __shfl_xor(vs, 4); vs += __shfl_xor(vs, 8);
                vd += __shfl_xor(vd, 1); vd += __shfl_xor(vd, 2);
                vd += __shfl_xor(vd, 4); vd += __shfl_xor(vd, 8);
                if (l15 == 0) {
                    int row = rowBase + i * 16 + kg * 4 + q2;
                    if (row < M) {
                        atomicAdd(&als[row * H + head], vs);
                        atomicAdd(&ald[row * H + head], vd);
                    }
                }
            }
    } else {
        const int cb2 = NB1 * 128;
#pragma unroll
        for (int i = 0; i < 4; i++)
#pragma unroll
            for (int j = 0; j < 4; j++) {
                int c2 = colBase + j * 16 + l15 - cb2;
                float bsum = bias1[c2] + bias2[c2];
#pragma unroll
                for (int q2 = 0; q2 < 4; q2++) {
                    int row = rowBase + i * 16 + kg * 4 + q2;
                    if (row < M) C2[(size_t)row * N2 + c2] = acc[i][j][q2] + bsum;
                }
            }
    }
}

// --------------------------- fused edge-softmax + aggregation (wave/node)
// ONE WAVE per dst node: no LDS, no barriers. Lane e owns edge e of each
// 64-edge chunk (online-softmax rescale across chunks); softmax via 64-lane
// shfl trees; aggregation broadcasts (src, p) via shfl while all 64 lanes
// read that row's columns coalesced.
//  H=4: lane owns 16 cols (lane*16..+15), 2x f16x8 per edge.
//  H=6: lane owns 3x8 cols (b*512 + lane*8), 3x f16x8 per edge;
//       head-mean via shfl_xor(32) pairing.
template <int H, bool MEAN>
__global__ __launch_bounds__(256) void smagg_k(const int* __restrict__ offs,
                                               const int* __restrict__ esrc,
                                               const float* __restrict__ als,
                                               const float* __restrict__ ald,
                                               const f16* __restrict__ hfeat16,
                                               const float* __restrict__ skipin,
                                               float* __restrict__ outf,
                                               f16* __restrict__ hiT,
                                               f16* __restrict__ loT) {
    constexpr int NC = H * 256;
    const int lane = threadIdx.x & 63;
    const int n = blockIdx.x * 4 + (threadIdx.x >> 6);
    const int base = offs[n], cnt = offs[n + 1] - base;

    float ad[H];
#pragma unroll
    for (int h = 0; h < H; h++) ad[h] = ald[n * H + h];

    float m[H], ssum[H];
#pragma unroll
    for (int h = 0; h < H; h++) { m[h] = -1e30f; ssum[h] = 0.f; }

    float acc4[16];
    float acc6[3][8];
    if (H == 4) {
#pragma unroll
        for (int i = 0; i < 16; i++) acc4[i] = 0.f;
    } else {
#pragma unroll
        for (int b = 0; b < 3; b++)
#pragma unroll
            for (int j = 0; j < 8; j++) acc6[b][j] = 0.f;
    }
    const int h0 = lane >> 4;                 // H=4: head of owned cols
    const int par = (lane >= 32) ? 1 : 0;     // H=6: head parity of owned cols

    for (int c0 = 0; c0 < cnt; c0 += 64) {
        const int mcnt = min(64, cnt - c0);
        int src = 0;
        float l[H];
        if (lane < mcnt) {
            src = esrc[base + c0 + lane];
            if (H == 4) {
                float4 a4 = *(const float4*)(als + (size_t)src * 4);
                l[0] = a4.x + ad[0]; l[1] = a4.y + ad[1];
                l[2] = a4.z + ad[2]; l[3] = a4.w + ad[3];
            } else {
                const float2* ap = (const float2*)(als + (size_t)src * 6);
#pragma unroll
                for (int b = 0; b < 3; b++) {
                    float2 a2 = ap[b];
                    l[2 * b]     = a2.x + ad[2 * b];
                    l[2 * b + 1] = a2.y + ad[2 * b + 1];
                }
            }
#pragma unroll
            for (int h = 0; h < H; h++) l[h] = (l[h] < 0.f) ? 0.2f * l[h] : l[h];
        } else {
#pragma unroll
            for (int h = 0; h < H; h++) l[h] = -1e30f;
        }
        // per-head max across wave + online rescale
        float sc[H], p[H];
#pragma unroll
        for (int h = 0; h < H; h++) {
            float v = l[h];
            for (int o = 32; o > 0; o >>= 1) v = fmaxf(v, __shfl_xor(v, o, 64));
            float mN = fmaxf(m[h], v);
            sc[h] = __expf(m[h] - mN);
            m[h] = mN;
            p[h] = (lane < mcnt) ? __expf(l[h] - mN) : 0.f;
            float s = p[h];
            for (int o = 32; o > 0; o >>= 1) s += __shfl_xor(s, o, 64);
            ssum[h] = ssum[h] * sc[h] + s;
        }
        if (H == 4) {
            float scm = (h0 < 2) ? ((h0 == 0) ? sc[0] : sc[1])
                                 : ((h0 == 2) ? sc[2] : sc[3]);
#pragma unroll
            for (int i = 0; i < 16; i++) acc4[i] *= scm;
        } else {
#pragma unroll
            for (int b = 0; b < 3; b++) {
                float scm = par ? sc[2 * b + 1] : sc[2 * b];
#pragma unroll
                for (int j = 0; j < 8; j++) acc6[b][j] *= scm;
            }
        }
        // aggregation: broadcast (src, p) per edge, coalesced row read
        for (int e = 0; e < mcnt; e++) {
            int se = __shfl(src, e, 64);
            if (H == 4) {
                float pe0 = __shfl(p[0], e, 64), pe1 = __shfl(p[1], e, 64);
                float pe2 = __shfl(p[2], e, 64), pe3 = __shfl(p[3], e, 64);
                float ph = (h0 < 2) ? ((h0 == 0) ? pe0 : pe1)
                                    : ((h0 == 2) ? pe2 : pe3);
                const f16* hp = hfeat16 + (size_t)se * 1024 + lane * 16;
                f16x8 v0 = *(const f16x8*)hp;
                f16x8 v1 = *(const f16x8*)(hp + 8);
#pragma unroll
                for (int i = 0; i < 8; i++) {
                    acc4[i]     += ph * (float)v0[i];
                    acc4[8 + i] += ph * (float)v1[i];
                }
            } else {
                float pe[6];
#pragma unroll
                for (int h = 0; h < 6; h++) pe[h] = __shfl(p[h], e, 64);
                const f16* hp = hfeat16 + (size_t)se * 1536 + lane * 8;
#pragma unroll
                for (int b = 0; b < 3; b++) {
                    float ph = par ? pe[2 * b + 1] : pe[2 * b];
                    f16x8 v = *(const f16x8*)(hp + b * 512);
#pragma unroll
                    for (int j = 0; j < 8; j++) acc6[b][j] += ph * (float)v[j];
                }
            }
        }
    }

    if (MEAN) {
        float pt[8];
#pragma unroll
        for (int j = 0; j < 8; j++) pt[j] = 0.f;
#pragma unroll
        for (int b = 0; b < 3; b++) {
            float inv = 1.f / (ssum[par ? 2 * b + 1 : 2 * b] + 1e-16f);
#pragma unroll
            for (int j = 0; j < 8; j++) pt[j] += acc6[b][j] * inv;
        }
#pragma unroll
        for (int j = 0; j < 8; j++) pt[j] += __shfl_xor(pt[j], 32, 64);
        if (lane < 32) {
            float* op = outf + (size_t)n * 256 + lane * 8;
            float4 o0 = *(float4*)op, o1 = *(float4*)(op + 4);
            o0.x += pt[0] * (1.f / 6.f); o0.y += pt[1] * (1.f / 6.f);
            o0.z += pt[2] * (1.f / 6.f); o0.w += pt[3] * (1.f / 6.f);
            o1.x += pt[4] * (1.f / 6.f); o1.y += pt[5] * (1.f / 6.f);
            o1.z += pt[6] * (1.f / 6.f); o1.w += pt[7] * (1.f / 6.f);
            *(float4*)op = o0; *(float4*)(op + 4) = o1;
        }
    } else {
        // skip + agg -> ELU -> next layer's tiled hi/lo A
        float inv = 1.f / (ssum[(h0 < 2) ? ((h0 == 0) ? 0 : 1)
                                         : ((h0 == 2) ? 2 : 3)] + 1e-16f);
        const float* sp = skipin + (size_t)n * 1024 + lane * 16;
        float v[16];
#pragma unroll
        for (int c = 0; c < 4; c++) {
            float4 sk = *(const float4*)(sp + c * 4);
            v[c * 4 + 0] = sk.x + acc4[c * 4 + 0] * inv;
            v[c * 4 + 1] = sk.y + acc4[c * 4 + 1] * inv;
            v[c * 4 + 2] = sk.z + acc4[c * 4 + 2] * inv;
            v[c * 4 + 3] = sk.w + acc4[c * 4 + 3] * inv;
        }
        f16x8 hv0, lv0, hv1, lv1;
#pragma unroll
        for (int i = 0; i < 8; i++) {
            float e0 = (v[i] > 0.f) ? v[i] : expf(v[i]) - 1.f;
            float e1 = (v[8 + i] > 0.f) ? v[8 + i] : expf(v[8 + i]) - 1.f;
            f16 h0f = (f16)e0, h1f = (f16)e1;
            hv0[i] = h0f; lv0[i] = (f16)(e0 - (float)h0f);
            hv1[i] = h1f; lv1[i] = (f16)(e1 - (float)h1f);
        }
        const int mblk = n >> 7, r = n & 127;
        const int kblk = lane >> 1, ko0 = (lane & 1) * 2;
        size_t tb = ((size_t)(mblk * 32 + kblk)) * 4096 + r * 32;
        size_t off0 = tb + swz(r, ko0) * 8;
        size_t off1 = tb + swz(r, ko0 + 1) * 8;
        *(f16x8*)(hiT + off0) = hv0;
        *(f16x8*)(hiT + off1) = hv1;
        *(f16x8*)(loT + off0) = lv0;
        *(f16x8*)(loT + off1) = lv1;
    }
}

// ------------------------------------------------------------------ driver
extern "C" void kernel_launch(void* const* d_in, const int* in_sizes, int n_in,
                              void* d_out, int out_size, void* d_ws, size_t ws_size,
                              hipStream_t stream) {
    const float* x   = (const float*)d_in[0];
    const int*   ei  = (const int*)d_in[1];
    const float* W1  = (const float*)d_in[2];
    const float* a1s = (const float*)d_in[3];
    const float* a1d = (const float*)d_in[4];
    const float* b1  = (const float*)d_in[5];
    const float* S1w = (const float*)d_in[6];
    const float* S1b = (const float*)d_in[7];
    const float* W2  = (const float*)d_in[8];
    const float* a2s = (const float*)d_in[9];
    const float* a2d = (const float*)d_in[10];
    const float* b2  = (const float*)d_in[11];
    const float* S2w = (const float*)d_in[12];
    const float* S2b = (const float*)d_in[13];
    const float* W3  = (const float*)d_in[14];
    const float* a3s = (const float*)d_in[15];
    const float* a3d = (const float*)d_in[16];
    const float* b3  = (const float*)d_in[17];
    const float* S3w = (const float*)d_in[18];
    const float* S3b = (const float*)d_in[19];
    float* out = (float*)d_out;

    float* ws = (float*)d_ws;
    size_t o = 0;
    float* bufA = ws + o; o += (size_t)NN * 1024;   // skip outputs (C2)
    float* bufB = ws + o; o += (size_t)NN * 1024;
    float* als  = ws + o; o += (size_t)NN * 6;
    float* ald  = ws + o; o += (size_t)NN * 6;
    f16* hfeat16 = (f16*)(ws + o); o += (size_t)MPAD * 1536 / 2;
    f16* AhiT = (f16*)(ws + o); o += (size_t)MPAD * 1024 / 2;
    f16* AloT = (f16*)(ws + o); o += (size_t)MPAD * 1024 / 2;
    f16* Bt1  = (f16*)(ws + o); o += (size_t)16 * 4  * 4096 / 2;
    f16* Bt2  = (f16*)(ws + o); o += (size_t)16 * 32 * 4096 / 2;
    f16* Bt3  = (f16*)(ws + o); o += (size_t)14 * 32 * 4096 / 2;
    int* deg   = (int*)(ws + o);
    int* tmp   = deg + NN;
    int* bsum  = tmp + NN;
    int* bbase = bsum + 64;
    int* offs  = bbase + 64;
    int* pos   = offs + NN + 1;
    int* esrc  = pos + NN;

    // ---- CSR by dst (shared by all 3 layers)
    hipMemsetAsync(deg, 0, NN * sizeof(int), stream);
    count_deg_k<<<(ETOT + 255) / 256, 256, 0, stream>>>(ei, deg);
    sc1_k<<<40, 256, 0, stream>>>(deg, tmp, bsum);
    sc2_k<<<1, 64, 0, stream>>>(bsum, bbase);
    sc3_k<<<40, 256, 0, stream>>>(deg, tmp, bbase, offs, pos);
    scatter_k<<<(ETOT + 255) / 256, 256, 0, stream>>>(ei, pos, esrc);

    // ---- weight conversion (merged per-layer B = [W | S], hi only)
    convB_k<<<dim3(4, 16),  256, 0, stream>>>(W1,  Bt1, 1024, 0,    4);
    convB_k<<<dim3(4, 16),  256, 0, stream>>>(S1w, Bt1, 1024, 1024, 4);
    convB_k<<<dim3(4, 128), 256, 0, stream>>>(W2,  Bt2, 1024, 0,    32);
    convB_k<<<dim3(4, 128), 256, 0, stream>>>(S2w, Bt2, 1024, 1024, 32);
    convB_k<<<dim3(6, 128), 256, 0, stream>>>(W3,  Bt3, 1536, 0,    32);
    convB_k<<<dim3(1, 128), 256, 0, stream>>>(S3w, Bt3, 256,  1536, 32);

    // ---- Layer 1: A=x [N,128], N=2048 (8 blk feat | 8 blk skip)
    convA_k<false><<<MPAD * 16 / 256, 256, 0, stream>>>(x, AhiT, AloT, NN, 128, 4);
    hipMemsetAsync(als, 0, NN * 12 * sizeof(float), stream);
    mm_k<<<dim3(16, 79), 256, 0, stream>>>(AhiT, AloT, Bt1, bufA, hfeat16, S1b, b1,
                                           a1s, a1d, als, ald,
                                           NN, 4, 8, 1024, 1024, 4);
    // smagg writes layer-2's tiled A (ELU fused), consuming skip from bufA
    smagg_k<4, false><<<NN / 4, 256, 0, stream>>>(offs, esrc, als, ald, hfeat16,
                                                  bufA, nullptr, AhiT, AloT);

    // ---- Layer 2
    hipMemsetAsync(als, 0, NN * 12 * sizeof(float), stream);
    mm_k<<<dim3(16, 79), 256, 0, stream>>>(AhiT, AloT, Bt2, bufB, hfeat16, S2b, b2,
                                           a2s, a2d, als, ald,
                                           NN, 32, 8, 1024, 1024, 4);
    smagg_k<4, false><<<NN / 4, 256, 0, stream>>>(offs, esrc, als, ald, hfeat16,
                                                  bufB, nullptr, AhiT, AloT);

    // ---- Layer 3: N=1792 (12 blk feat | 2 blk skip->out), mean over 6 heads
    hipMemsetAsync(als, 0, NN * 12 * sizeof(float), stream);
    mm_k<<<dim3(14, 79), 256, 0, stream>>>(AhiT, AloT, Bt3, out, hfeat16, S3b, b3,
                                           a3s, a3d, als, ald,
                                           NN, 32, 12, 1536, 256, 6);
    smagg_k<6, true><<<NN / 4, 256, 0, stream>>>(offs, esrc, als, ald, hfeat16,
                                                 nullptr, out, nullptr, nullptr);
}

// Round 9
// 545.643 us; speedup vs baseline: 1.0311x; 1.0291x over previous
//
#include <hip/hip_runtime.h>
#include <cfloat>
#include <cmath>
#include <cstdint>

#define NN 10000
#define EE 160000
#define ETOT 170000   // EE + NN self loops
#define MPAD 10112    // 79*128

typedef _Float16 f16;
typedef __attribute__((ext_vector_type(8))) _Float16 f16x8;
typedef __attribute__((ext_vector_type(4))) float f32x4;

// ---------------------------------------------------------------- CSR build
__global__ __launch_bounds__(256) void count_deg_k(const int* __restrict__ ei,
                                                   int* __restrict__ deg) {
    int e = blockIdx.x * 256 + threadIdx.x;
    if (e < ETOT) {
        int dst = (e < EE) ? ei[EE + e] : (e - EE);
        atomicAdd(&deg[dst], 1);
    }
}

__global__ __launch_bounds__(256) void sc1_k(const int* __restrict__ deg,
                                             int* __restrict__ tmp,
                                             int* __restrict__ bsum) {
    __shared__ int s[256];
    int i = blockIdx.x * 256 + threadIdx.x;
    int v = (i < NN) ? deg[i] : 0;
    s[threadIdx.x] = v;
    __syncthreads();
    for (int d = 1; d < 256; d <<= 1) {
        int t = (threadIdx.x >= d) ? s[threadIdx.x - d] : 0;
        __syncthreads();
        s[threadIdx.x] += t;
        __syncthreads();
    }
    if (i < NN) tmp[i] = s[threadIdx.x];
    if (threadIdx.x == 255) bsum[blockIdx.x] = s[255];
}

__global__ __launch_bounds__(64) void sc2_k(const int* __restrict__ bsum,
                                            int* __restrict__ bbase) {
    int lane = threadIdx.x;
    int v = (lane < 40) ? bsum[lane] : 0;
    int incl = v;
    for (int d = 1; d < 64; d <<= 1) {
        int t = __shfl_up(incl, d, 64);
        if (lane >= d) incl += t;
    }
    if (lane < 40) bbase[lane] = incl - v;
}

__global__ __launch_bounds__(256) void sc3_k(const int* __restrict__ deg,
                                             const int* __restrict__ tmp,
                                             const int* __restrict__ bbase,
                                             int* __restrict__ offs,
                                             int* __restrict__ pos) {
    int i = blockIdx.x * 256 + threadIdx.x;
    if (i < NN) {
        int incl = tmp[i] + bbase[blockIdx.x];
        offs[i + 1] = incl;
        pos[i]      = incl - deg[i];
    }
    if (i == 0) offs[0] = 0;
}

__global__ __launch_bounds__(256) void scatter_k(const int* __restrict__ ei,
                                                 int* __restrict__ pos,
                                                 int* __restrict__ esrc) {
    int e = blockIdx.x * 256 + threadIdx.x;
    if (e < ETOT) {
        int dst = (e < EE) ? ei[EE + e] : (e - EE);
        int src = (e < EE) ? ei[e]      : (e - EE);
        int p = atomicAdd(&pos[dst], 1);
        esrc[p] = src;
    }
}

// --------------------------------------------- fp32 -> tiled f16 hi/lo
// Tile = 128 rows x 32 k (8KB). Row r at r*64B; 16B chunk ko at ko^((r>>1)&3).
__device__ __forceinline__ int swz(int r, int ko) { return ko ^ ((r >> 1) & 3); }

// Layer-1 A conversion; also zeroes the slot-0 logit buffers (atomics target).
__global__ __launch_bounds__(256) void convA_k(const float* __restrict__ A,
                                               f16* __restrict__ hi,
                                               f16* __restrict__ lo,
                                               float* __restrict__ z1,
                                               float* __restrict__ z2,
                                               int M, int K, int kshift) {
    int idx = blockIdx.x * 256 + threadIdx.x;
    if (idx < NN * 6) z1[idx] = 0.f;
    else if (idx < NN * 12) z2[idx - NN * 6] = 0.f;
    int row = idx >> kshift;
    int kc  = idx & ((1 << kshift) - 1);
    float v[8];
    if (row < M) {
        const float* p = A + (size_t)row * K + kc * 8;
        float4 f0 = *(const float4*)p, f1 = *(const float4*)(p + 4);
        v[0]=f0.x; v[1]=f0.y; v[2]=f0.z; v[3]=f0.w;
        v[4]=f1.x; v[5]=f1.y; v[6]=f1.z; v[7]=f1.w;
    } else {
#pragma unroll
        for (int i = 0; i < 8; i++) v[i] = 0.f;
    }
    int mblk = row >> 7, r = row & 127;
    int kblk = kc >> 2,  ko = kc & 3;
    int KB = K >> 5;
    size_t off = ((size_t)(mblk * KB + kblk)) * 4096 + r * 32 + swz(r, ko) * 8;
    f16x8 h, l;
#pragma unroll
    for (int i = 0; i < 8; i++) {
        f16 hv = (f16)v[i];
        h[i] = hv;
        l[i] = (f16)(v[i] - (float)hv);
    }
    *(f16x8*)(hi + off) = h;
    *(f16x8*)(lo + off) = l;
}

// All six B conversions in ONE dispatch (2048 blocks, segment table).
__global__ __launch_bounds__(256) void convB_all_k(const float* __restrict__ W1,
                                                   const float* __restrict__ S1w,
                                                   const float* __restrict__ W2,
                                                   const float* __restrict__ S2w,
                                                   const float* __restrict__ W3,
                                                   const float* __restrict__ S3w,
                                                   f16* __restrict__ Bt1,
                                                   f16* __restrict__ Bt2,
                                                   f16* __restrict__ Bt3) {
    int bid = blockIdx.x;
    const float* B; f16* Bdst; int NcSrc, colOff, KB, nbx, sbid;
    if (bid < 64)        { B = W1;  Bdst = Bt1; NcSrc = 1024; colOff = 0;    KB = 4;  nbx = 4; sbid = bid; }
    else if (bid < 128)  { B = S1w; Bdst = Bt1; NcSrc = 1024; colOff = 1024; KB = 4;  nbx = 4; sbid = bid - 64; }
    else if (bid < 640)  { B = W2;  Bdst = Bt2; NcSrc = 1024; colOff = 0;    KB = 32; nbx = 4; sbid = bid - 128; }
    else if (bid < 1152) { B = S2w; Bdst = Bt2; NcSrc = 1024; colOff = 1024; KB = 32; nbx = 4; sbid = bid - 640; }
    else if (bid < 1920) { B = W3;  Bdst = Bt3; NcSrc = 1536; colOff = 0;    KB = 32; nbx = 6; sbid = bid - 1152; }
    else                 { B = S3w; Bdst = Bt3; NcSrc = 256;  colOff = 1536; KB = 32; nbx = 1; sbid = bid - 1920; }
    int bx = sbid % nbx, kc = sbid / nbx;
    int n = bx * 256 + threadIdx.x;
    const float* p = B + (size_t)(kc * 8) * NcSrc + n;
    int gcol = colOff + n;
    int nblk = gcol >> 7, r = gcol & 127;
    int kblk = kc >> 2,  ko = kc & 3;
    size_t off = ((size_t)(nblk * KB + kblk)) * 4096 + r * 32 + swz(r, ko) * 8;
    f16x8 h;
#pragma unroll
    for (int i = 0; i < 8; i++) h[i] = (f16)p[(size_t)i * NcSrc];
    *(f16x8*)(Bdst + off) = h;
}

// ---------------------------------------------------------- f16 MFMA GEMM
// C = (Ahi+Alo)*Bhi. 128x128 tile, BK=32, EIGHT waves (4x2, 32x64 wave-tile).
// 2-phase pipeline, double-buffered LDS (2x24KB -> 2 blocks/CU = 16 waves/CU).
__device__ __forceinline__ void gl_lds16(const void* g, void* l) {
    __builtin_amdgcn_global_load_lds(
        (const __attribute__((address_space(1))) uint32_t*)g,
        (__attribute__((address_space(3))) uint32_t*)l, 16, 0, 0);
}

#define MMBUF 24576

__global__ __launch_bounds__(512) void mm_k(const f16* __restrict__ Ahi,
                                            const f16* __restrict__ Alo,
                                            const f16* __restrict__ Bhi,
                                            float* __restrict__ C2,
                                            f16* __restrict__ C1h,
                                            const float* __restrict__ bias1,
                                            const float* __restrict__ bias2,
                                            const float* __restrict__ a_s,
                                            const float* __restrict__ a_d,
                                            float* __restrict__ als,
                                            float* __restrict__ ald,
                                            int M, int KB, int NB1,
                                            int N1, int N2) {
    __shared__ __align__(16) char lds[2 * MMBUF];  // per buf: Ahi|Alo|Bhi 8KB each
    const int tid = threadIdx.x;

    // bijective XCD chunking: consecutive remapped ids share mblk on one XCD
    const int nwg  = gridDim.x * gridDim.y;
    const int orig = blockIdx.y * gridDim.x + blockIdx.x;
    const int q = nwg >> 3, rr = nwg & 7;
    const int xcd = orig & 7, rk = orig >> 3;
    const int lin = (xcd < rr ? xcd * (q + 1) : rr * (q + 1) + (xcd - rr) * q) + rk;
    const int mblk = lin / gridDim.x, nblk = lin % gridDim.x;

    const int lane = tid & 63, w = tid >> 6;
    const int wr = w >> 1, wc = w & 1;          // 4 x 2 waves, tile 32x64
    const int kg = lane >> 4, l15 = lane & 15;

    int offA[2], offB[4];
#pragma unroll
    for (int t = 0; t < 2; t++) {
        int ra = wr * 32 + t * 16 + l15;
        offA[t] = ra * 64 + swz(ra, kg) * 16;
    }
#pragma unroll
    for (int t = 0; t < 4; t++) {
        int rb = wc * 64 + t * 16 + l15;
        offB[t] = 16384 + rb * 64 + swz(rb, kg) * 16;
    }

    const char* gAh = (const char*)Ahi + (size_t)mblk * KB * 8192;
    const char* gAl = (const char*)Alo + (size_t)mblk * KB * 8192;
    const char* gBh = (const char*)Bhi + (size_t)nblk * KB * 8192;

    f32x4 acc[2][4];
#pragma unroll
    for (int i = 0; i < 2; i++)
#pragma unroll
        for (int j = 0; j < 4; j++) acc[i][j] = (f32x4){0.f, 0.f, 0.f, 0.f};

    const int t16 = tid * 16;                   // 512 threads x 16B = 8KB/call
    auto stage = [&](int kb, int buf) {
        const size_t tk = (size_t)kb * 8192;
        char* l = lds + buf * MMBUF;
        gl_lds16(gAh + tk + t16, l + t16);
        gl_lds16(gAl + tk + t16, l + 8192 + t16);
        gl_lds16(gBh + tk + t16, l + 16384 + t16);
    };

    stage(0, 0);
    __syncthreads();

    for (int kb = 0; kb < KB; kb++) {
        const int cur = kb & 1;
        if (kb + 1 < KB) stage(kb + 1, cur ^ 1);   // in flight across compute

        const char* l = lds + cur * MMBUF;
        f16x8 ah[2], al[2], b[4];
#pragma unroll
        for (int t = 0; t < 2; t++) {
            ah[t] = *(const f16x8*)(l + offA[t]);
            al[t] = *(const f16x8*)(l + 8192 + offA[t]);
        }
#pragma unroll
        for (int t = 0; t < 4; t++) b[t] = *(const f16x8*)(l + offB[t]);
#pragma unroll
        for (int i = 0; i < 2; i++)
#pragma unroll
            for (int j = 0; j < 4; j++) {
                acc[i][j] = __builtin_amdgcn_mfma_f32_16x16x32_f16(ah[i], b[j], acc[i][j], 0, 0, 0);
                acc[i][j] = __builtin_amdgcn_mfma_f32_16x16x32_f16(al[i], b[j], acc[i][j], 0, 0, 0);
            }
        __syncthreads();
    }

    const int rowBase = mblk * 128 + wr * 32;
    const int colBase = nblk * 128 + wc * 64;
    if (nblk < NB1) {
        // f16 feature write (garbage pad rows never read downstream)
#pragma unroll
        for (int i = 0; i < 2; i++)
#pragma unroll
            for (int j = 0; j < 4; j++) {
                int col = colBase + j * 16 + l15;
#pragma unroll
                for (int q2 = 0; q2 < 4; q2++) {
                    int row = rowBase + i * 16 + kg * 4 + q2;
                    C1h[(size_t)row * N1 + col] = (f16)acc[i][j][q2];
                }
            }
        // fused attention logits (als/ald stride-6, zeroed slot)
        const int head = nblk >> 1;
        const int cIn  = (nblk & 1) * 128 + wc * 64;
        float asv[4], adv[4];
#pragma unroll
        for (int j = 0; j < 4; j++) {
            asv[j] = a_s[head * 256 + cIn + j * 16 + l15];
            adv[j] = a_d[head * 256 + cIn + j * 16 + l15];
        }
#pragma unroll
        for (int i = 0; i < 2; i++)
#pragma unroll
            for (int q2 = 0; q2 < 4; q2++) {
                float vs = acc[i][0][q2] * asv[0] + acc[i][1][q2] * asv[1]
                         + acc[i][2][q2] * asv[2] + acc[i][3][q2] * asv[3];
                float vd = acc[i][0][q2] * adv[0] + acc[i][1][q2] * adv[1]
                         + acc[i][2][q2] * adv[2] + acc[i][3][q2] * adv[3];
                vs += __shfl_xor(vs, 1); vs += __shfl_xor(vs, 2);
                vs += __shfl_xor(vs, 4); vs += __shfl_xor(vs, 8);
                vd += __shfl_xor(vd, 1); vd += __shfl_xor(vd, 2);
                vd += __shfl_xor(vd, 4); vd += __shfl_xor(vd, 8);
                if (l15 == 0) {
                    int row = rowBase + i * 16 + kg * 4 + q2;
                    if (row < M) {
                        atomicAdd(&als[row * 6 + head], vs);
                        atomicAdd(&ald[row * 6 + head], vd);
                    }
                }
            }
    } else {
        const int cb2 = NB1 * 128;
#pragma unroll
        for (int i = 0; i < 2; i++)
#pragma unroll
            for (int j = 0; j < 4; j++) {
                int c2 = colBase + j * 16 + l15 - cb2;
                float bsum = bias1[c2] + bias2[c2];
#pragma unroll
                for (int q2 = 0; q2 < 4; q2++) {
                    int row = rowBase + i * 16 + kg * 4 + q2;
                    if (row < M) C2[(size_t)row * N2 + c2] = acc[i][j][q2] + bsum;
                }
            }
    }
}

// --------------------------- fused edge-softmax + aggregation (wave/node)
// ONE WAVE per dst node, no LDS/barriers. als/ald stride 6, double-buffered
// slots: reads slot S, zeroes slot S^1 for the next layer's mm atomics.
template <int H, bool MEAN>
__global__ __launch_bounds__(256) void smagg_k(const int* __restrict__ offs,
                                               const int* __restrict__ esrc,
                                               const float* __restrict__ als,
                                               const float* __restrict__ ald,
                                               float* __restrict__ alsN,
                                               float* __restrict__ aldN,
                                               const f16* __restrict__ hfeat16,
                                               const float* __restrict__ skipin,
                                               float* __restrict__ outf,
                                               f16* __restrict__ hiT,
                                               f16* __restrict__ loT) {
    const int lane = threadIdx.x & 63;
    const int n = blockIdx.x * 4 + (threadIdx.x >> 6);
    const int base = offs[n], cnt = offs[n + 1] - base;

    // zero the next layer's logit slot (no memset dispatch needed)
    if (alsN) {
        if (lane < 6) alsN[n * 6 + lane] = 0.f;
        else if (lane < 12) aldN[n * 6 + lane - 6] = 0.f;
    }

    float ad[H];
#pragma unroll
    for (int h = 0; h < H; h++) ad[h] = ald[n * 6 + h];

    float m[H], ssum[H];
#pragma unroll
    for (int h = 0; h < H; h++) { m[h] = -1e30f; ssum[h] = 0.f; }

    float acc4[16];
    float acc6[3][8];
    if (H == 4) {
#pragma unroll
        for (int i = 0; i < 16; i++) acc4[i] = 0.f;
    } else {
#pragma unroll
        for (int b = 0; b < 3; b++)
#pragma unroll
            for (int j = 0; j < 8; j++) acc6[b][j] = 0.f;
    }
    const int h0 = lane >> 4;                 // H=4: head of owned cols
    const int par = (lane >= 32) ? 1 : 0;     // H=6: head parity of owned cols

    for (int c0 = 0; c0 < cnt; c0 += 64) {
        const int mcnt = min(64, cnt - c0);
        int src = 0;
        float l[H];
        if (lane < mcnt) {
            src = esrc[base + c0 + lane];
            const float2* ap = (const float2*)(als + (size_t)src * 6);
            if (H == 4) {
                float2 a01 = ap[0], a23 = ap[1];
                l[0] = a01.x + ad[0]; l[1] = a01.y + ad[1];
                l[2] = a23.x + ad[2]; l[3] = a23.y + ad[3];
            } else {
#pragma unroll
                for (int b = 0; b < 3; b++) {
                    float2 a2 = ap[b];
                    l[2 * b]     = a2.x + ad[2 * b];
                    l[2 * b + 1] = a2.y + ad[2 * b + 1];
                }
            }
#pragma unroll
            for (int h = 0; h < H; h++) l[h] = (l[h] < 0.f) ? 0.2f * l[h] : l[h];
        } else {
#pragma unroll
            for (int h = 0; h < H; h++) l[h] = -1e30f;
        }
        // per-head max across wave + online rescale
        float sc[H], p[H];
#pragma unroll
        for (int h = 0; h < H; h++) {
            float v = l[h];
            for (int o = 32; o > 0; o >>= 1) v = fmaxf(v, __shfl_xor(v, o, 64));
            float mN = fmaxf(m[h], v);
            sc[h] = __expf(m[h] - mN);
            m[h] = mN;
            p[h] = (lane < mcnt) ? __expf(l[h] - mN) : 0.f;
            float s = p[h];
            for (int o = 32; o > 0; o >>= 1) s += __shfl_xor(s, o, 64);
            ssum[h] = ssum[h] * sc[h] + s;
        }
        if (H == 4) {
            float scm = (h0 < 2) ? ((h0 == 0) ? sc[0] : sc[1])
                                 : ((h0 == 2) ? sc[2] : sc[3]);
#pragma unroll
            for (int i = 0; i < 16; i++) acc4[i] *= scm;
        } else {
#pragma unroll
            for (int b = 0; b < 3; b++) {
                float scm = par ? sc[2 * b + 1] : sc[2 * b];
#pragma unroll
                for (int j = 0; j < 8; j++) acc6[b][j] *= scm;
            }
        }
        // aggregation: broadcast (src, p) per edge, coalesced row read
        for (int e = 0; e < mcnt; e++) {
            int se = __shfl(src, e, 64);
            if (H == 4) {
                float pe0 = __shfl(p[0], e, 64), pe1 = __shfl(p[1], e, 64);
                float pe2 = __shfl(p[2], e, 64), pe3 = __shfl(p[3], e, 64);
                float ph = (h0 < 2) ? ((h0 == 0) ? pe0 : pe1)
                                    : ((h0 == 2) ? pe2 : pe3);
                const f16* hp = hfeat16 + (size_t)se * 1024 + lane * 16;
                f16x8 v0 = *(const f16x8*)hp;
                f16x8 v1 = *(const f16x8*)(hp + 8);
#pragma unroll
                for (int i = 0; i < 8; i++) {
                    acc4[i]     += ph * (float)v0[i];
                    acc4[8 + i] += ph * (float)v1[i];
                }
            } else {
                float pe[6];
#pragma unroll
                for (int h = 0; h < 6; h++) pe[h] = __shfl(p[h], e, 64);
                const f16* hp = hfeat16 + (size_t)se * 1536 + lane * 8;
#pragma unroll
                for (int b = 0; b < 3; b++) {
                    float ph = par ? pe[2 * b + 1] : pe[2 * b];
                    f16x8 v = *(const f16x8*)(hp + b * 512);
#pragma unroll
                    for (int j = 0; j < 8; j++) acc6[b][j] += ph * (float)v[j];
                }
            }
        }
    }

    if (MEAN) {
        float pt[8];
#pragma unroll
        for (int j = 0; j < 8; j++) pt[j] = 0.f;
#pragma unroll
        for (int b = 0; b < 3; b++) {
            float inv = 1.f / (ssum[par ? 2 * b + 1 : 2 * b] + 1e-16f);
#pragma unroll
            for (int j = 0; j < 8; j++) pt[j] += acc6[b][j] * inv;
        }
#pragma unroll
        for (int j = 0; j < 8; j++) pt[j] += __shfl_xor(pt[j], 32, 64);
        if (lane < 32) {
            float* op = outf + (size_t)n * 256 + lane * 8;
            float4 o0 = *(float4*)op, o1 = *(float4*)(op + 4);
            o0.x += pt[0] * (1.f / 6.f); o0.y += pt[1] * (1.f / 6.f);
            o0.z += pt[2] * (1.f / 6.f); o0.w += pt[3] * (1.f / 6.f);
            o1.x += pt[4] * (1.f / 6.f); o1.y += pt[5] * (1.f / 6.f);
            o1.z += pt[6] * (1.f / 6.f); o1.w += pt[7] * (1.f / 6.f);
            *(float4*)op = o0; *(float4*)(op + 4) = o1;
        }
    } else {
        // skip + agg -> ELU -> next layer's tiled hi/lo A
        float inv = 1.f / (ssum[(h0 < 2) ? ((h0 == 0) ? 0 : 1)
                                         : ((h0 == 2) ? 2 : 3)] + 1e-16f);
        const float* sp = skipin + (size_t)n * 1024 + lane * 16;
        float v[16];
#pragma unroll
        for (int c = 0; c < 4; c++) {
            float4 sk = *(const float4*)(sp + c * 4);
            v[c * 4 + 0] = sk.x + acc4[c * 4 + 0] * inv;
            v[c * 4 + 1] = sk.y + acc4[c * 4 + 1] * inv;
            v[c * 4 + 2] = sk.z + acc4[c * 4 + 2] * inv;
            v[c * 4 + 3] = sk.w + acc4[c * 4 + 3] * inv;
        }
        f16x8 hv0, lv0, hv1, lv1;
#pragma unroll
        for (int i = 0; i < 8; i++) {
            float e0 = (v[i] > 0.f) ? v[i] : expf(v[i]) - 1.f;
            float e1 = (v[8 + i] > 0.f) ? v[8 + i] : expf(v[8 + i]) - 1.f;
            f16 h0f = (f16)e0, h1f = (f16)e1;
            hv0[i] = h0f; lv0[i] = (f16)(e0 - (float)h0f);
            hv1[i] = h1f; lv1[i] = (f16)(e1 - (float)h1f);
        }
        const int mblk = n >> 7, r = n & 127;
        const int kblk = lane >> 1, ko0 = (lane & 1) * 2;
        size_t tb = ((size_t)(mblk * 32 + kblk)) * 4096 + r * 32;
        size_t off0 = tb + swz(r, ko0) * 8;
        size_t off1 = tb + swz(r, ko0 + 1) * 8;
        *(f16x8*)(hiT + off0) = hv0;
        *(f16x8*)(hiT + off1) = hv1;
        *(f16x8*)(loT + off0) = lv0;
        *(f16x8*)(loT + off1) = lv1;
    }
}

// ------------------------------------------------------------------ driver
extern "C" void kernel_launch(void* const* d_in, const int* in_sizes, int n_in,
                              void* d_out, int out_size, void* d_ws, size_t ws_size,
                              hipStream_t stream) {
    const float* x   = (const float*)d_in[0];
    const int*   ei  = (const int*)d_in[1];
    const float* W1  = (const float*)d_in[2];
    const float* a1s = (const float*)d_in[3];
    const float* a1d = (const float*)d_in[4];
    const float* b1  = (const float*)d_in[5];
    const float* S1w = (const float*)d_in[6];
    const float* S1b = (const float*)d_in[7];
    const float* W2  = (const float*)d_in[8];
    const float* a2s = (const float*)d_in[9];
    const float* a2d = (const float*)d_in[10];
    const float* b2  = (const float*)d_in[11];
    const float* S2w = (const float*)d_in[12];
    const float* S2b = (const float*)d_in[13];
    const float* W3  = (const float*)d_in[14];
    const float* a3s = (const float*)d_in[15];
    const float* a3d = (const float*)d_in[16];
    const float* b3  = (const float*)d_in[17];
    const float* S3w = (const float*)d_in[18];
    const float* S3b = (const float*)d_in[19];
    float* out = (float*)d_out;

    float* ws = (float*)d_ws;
    size_t o = 0;
    float* bufA = ws + o; o += (size_t)NN * 1024;   // skip outputs (C2)
    float* bufB = ws + o; o += (size_t)NN * 1024;
    float* als0 = ws + o; o += (size_t)NN * 6;      // logit slot 0
    float* ald0 = ws + o; o += (size_t)NN * 6;
    float* als1 = ws + o; o += (size_t)NN * 6;      // logit slot 1
    float* ald1 = ws + o; o += (size_t)NN * 6;
    f16* hfeat16 = (f16*)(ws + o); o += (size_t)MPAD * 1536 / 2;
    f16* AhiT = (f16*)(ws + o); o += (size_t)MPAD * 1024 / 2;
    f16* AloT = (f16*)(ws + o); o += (size_t)MPAD * 1024 / 2;
    f16* Bt1  = (f16*)(ws + o); o += (size_t)16 * 4  * 4096 / 2;
    f16* Bt2  = (f16*)(ws + o); o += (size_t)16 * 32 * 4096 / 2;
    f16* Bt3  = (f16*)(ws + o); o += (size_t)14 * 32 * 4096 / 2;
    int* deg   = (int*)(ws + o);
    int* tmp   = deg + NN;
    int* bsum  = tmp + NN;
    int* bbase = bsum + 64;
    int* offs  = bbase + 64;
    int* pos   = offs + NN + 1;
    int* esrc  = pos + NN;

    // ---- CSR by dst (shared by all 3 layers)
    hipMemsetAsync(deg, 0, NN * sizeof(int), stream);
    count_deg_k<<<(ETOT + 255) / 256, 256, 0, stream>>>(ei, deg);
    sc1_k<<<40, 256, 0, stream>>>(deg, tmp, bsum);
    sc2_k<<<1, 64, 0, stream>>>(bsum, bbase);
    sc3_k<<<40, 256, 0, stream>>>(deg, tmp, bbase, offs, pos);
    scatter_k<<<(ETOT + 255) / 256, 256, 0, stream>>>(ei, pos, esrc);

    // ---- all weight conversions in one dispatch
    convB_all_k<<<2048, 256, 0, stream>>>(W1, S1w, W2, S2w, W3, S3w, Bt1, Bt2, Bt3);

    // ---- Layer 1: A=x [N,128], N=2048 (8 blk feat | 8 blk skip); zeroes slot0
    convA_k<<<MPAD * 16 / 256, 256, 0, stream>>>(x, AhiT, AloT, als0, ald0, NN, 128, 4);
    mm_k<<<dim3(16, 79), 512, 0, stream>>>(AhiT, AloT, Bt1, bufA, hfeat16, S1b, b1,
                                           a1s, a1d, als0, ald0, NN, 4, 8, 1024, 1024);
    smagg_k<4, false><<<NN / 4, 256, 0, stream>>>(offs, esrc, als0, ald0, als1, ald1,
                                                  hfeat16, bufA, nullptr, AhiT, AloT);

    // ---- Layer 2 (uses slot1; smagg zeroes slot0 for layer 3)
    mm_k<<<dim3(16, 79), 512, 0, stream>>>(AhiT, AloT, Bt2, bufB, hfeat16, S2b, b2,
                                           a2s, a2d, als1, ald1, NN, 32, 8, 1024, 1024);
    smagg_k<4, false><<<NN / 4, 256, 0, stream>>>(offs, esrc, als1, ald1, als0, ald0,
                                                  hfeat16, bufB, nullptr, AhiT, AloT);

    // ---- Layer 3: N=1792 (12 blk feat | 2 blk skip->out), mean over 6 heads
    mm_k<<<dim3(14, 79), 512, 0, stream>>>(AhiT, AloT, Bt3, out, hfeat16, S3b, b3,
                                           a3s, a3d, als0, ald0, NN, 32, 12, 1536, 256);
    smagg_k<6, true><<<NN / 4, 256, 0, stream>>>(offs, esrc, als0, ald0, nullptr, nullptr,
                                                 hfeat16, nullptr, out, nullptr, nullptr);
}